// Round 1
// baseline (3971.996 us; speedup 1.0000x reference)
//
#include <hip/hip_runtime.h>
#include <math.h>

#define B_SZ   4
#define T_SEQ  2048
#define EMB    1024
#define HEADS  16
#define HS     64
#define M_TOT  (B_SZ * T_SEQ)   // 8192

// ---------------------------------------------------------------------------
// GEMM: C = A @ W^T, A is MxK row-major, W is NxK row-major (torch Linear).
// Optional fused per-head LayerNorm epilogue (64-wide N tile == one head, each
// output tile row == one LN group) and optional bias.
// 64x64 tile, BK=32, 256 threads, 4x4 outputs/thread.
// ---------------------------------------------------------------------------
#define GT 64
#define GK 32

__global__ __launch_bounds__(256) void gemm_xwt(
    const float* __restrict__ A, const float* __restrict__ W,
    float* __restrict__ C, int K,
    const float* __restrict__ lng, const float* __restrict__ lnb,
    float post_scale, const float* __restrict__ bias, int do_ln)
{
    __shared__ float As[GT][GK + 4];   // pad 36: write ~balanced, read broadcast
    __shared__ float Bs[GT][GK + 4];
    const int tid = threadIdx.x;
    const int tx = tid & 15, ty = tid >> 4;
    const int m0 = blockIdx.x * GT, n0 = blockIdx.y * GT;

    float acc[4][4] = {{0.f, 0.f, 0.f, 0.f}, {0.f, 0.f, 0.f, 0.f},
                       {0.f, 0.f, 0.f, 0.f}, {0.f, 0.f, 0.f, 0.f}};

    for (int k0 = 0; k0 < K; k0 += GK) {
        #pragma unroll
        for (int i = 0; i < 2; ++i) {
            int f = tid + i * 256;          // 512 float4 per tile pair
            int r = f >> 3, c = (f & 7) << 2;
            *(float4*)&As[r][c] = *(const float4*)(A + (size_t)(m0 + r) * K + k0 + c);
            *(float4*)&Bs[r][c] = *(const float4*)(W + (size_t)(n0 + r) * K + k0 + c);
        }
        __syncthreads();
        #pragma unroll
        for (int kk = 0; kk < GK; ++kk) {
            float a[4], b[4];
            #pragma unroll
            for (int i = 0; i < 4; ++i) a[i] = As[ty * 4 + i][kk];
            #pragma unroll
            for (int j = 0; j < 4; ++j) b[j] = Bs[tx * 4 + j][kk];
            #pragma unroll
            for (int i = 0; i < 4; ++i)
                #pragma unroll
                for (int j = 0; j < 4; ++j)
                    acc[i][j] = fmaf(a[i], b[j], acc[i][j]);
        }
        __syncthreads();
    }

    if (do_ln) {
        // Each tile row = one (token, head) LN group of 64, spread over 16 tx lanes.
        #pragma unroll
        for (int i = 0; i < 4; ++i) {
            float s = acc[i][0] + acc[i][1] + acc[i][2] + acc[i][3];
            #pragma unroll
            for (int off = 1; off < 16; off <<= 1) s += __shfl_xor(s, off);
            float mu = s * (1.f / HS);
            float d2 = 0.f;
            #pragma unroll
            for (int j = 0; j < 4; ++j) { float d = acc[i][j] - mu; d2 += d * d; }
            #pragma unroll
            for (int off = 1; off < 16; off <<= 1) d2 += __shfl_xor(d2, off);
            float rs = rsqrtf(d2 * (1.f / HS) + 1e-5f);
            #pragma unroll
            for (int j = 0; j < 4; ++j) {
                int d = tx * 4 + j;
                acc[i][j] = ((acc[i][j] - mu) * rs * lng[d] + lnb[d]) * post_scale;
            }
        }
    }
    if (bias) {
        #pragma unroll
        for (int i = 0; i < 4; ++i)
            #pragma unroll
            for (int j = 0; j < 4; ++j)
                acc[i][j] += bias[n0 + tx * 4 + j];
    }
    #pragma unroll
    for (int i = 0; i < 4; ++i) {
        float4 v = make_float4(acc[i][0], acc[i][1], acc[i][2], acc[i][3]);
        *(float4*)(C + (size_t)(m0 + ty * 4 + i) * EMB + n0 + tx * 4) = v;
    }
}

// ---------------------------------------------------------------------------
// Flash attention, fp32. Block = (64 q-rows, head h, batch b), 256 threads.
// 4 lanes per q-row, each lane owns 16 of the 64 head dims.
// Online softmax; masked keys -> -inf; fully-masked query rows -> 0.
// ---------------------------------------------------------------------------
__global__ __launch_bounds__(256) void attn_fwd(
    const float* __restrict__ Q, const float* __restrict__ K,
    const float* __restrict__ V, const int* __restrict__ mask,
    float* __restrict__ O)
{
    __shared__ float Ks[64][68];
    __shared__ float Vs[64][68];
    __shared__ float Ps[64][65];
    __shared__ float kmsh[64];
    const int tid = threadIdx.x;
    const int qt = blockIdx.x, h = blockIdx.y, b = blockIdx.z;
    const int row = tid >> 2, sub = tid & 3;
    const int tq = qt * 64 + row;
    const int qm = mask[b * T_SEQ + tq];

    float qv[16];
    {
        const float* qp = Q + (size_t)(b * T_SEQ + tq) * EMB + h * HS + sub * 16;
        #pragma unroll
        for (int j = 0; j < 4; ++j) {
            float4 t4 = *(const float4*)(qp + j * 4);
            qv[j * 4 + 0] = t4.x; qv[j * 4 + 1] = t4.y;
            qv[j * 4 + 2] = t4.z; qv[j * 4 + 3] = t4.w;
        }
    }
    float mx = -INFINITY, sm = 0.f;
    float o[16];
    #pragma unroll
    for (int j = 0; j < 16; ++j) o[j] = 0.f;

    for (int kt = 0; kt < T_SEQ / 64; ++kt) {
        #pragma unroll
        for (int i = 0; i < 4; ++i) {
            int f = tid + i * 256;          // 1024 float4 per K/V tile
            int r = f >> 4, c = (f & 15) << 2;
            size_t g = (size_t)(b * T_SEQ + kt * 64 + r) * EMB + h * HS + c;
            *(float4*)&Ks[r][c] = *(const float4*)(K + g);
            *(float4*)&Vs[r][c] = *(const float4*)(V + g);
        }
        if (tid < 64) kmsh[tid] = (float)mask[b * T_SEQ + kt * 64 + tid];
        __syncthreads();

        if (qm) {
            float sreg[16];
            #pragma unroll
            for (int k = 0; k < 64; ++k) {   // full unroll: sreg stays in regs
                float s = 0.f;
                #pragma unroll
                for (int j = 0; j < 16; ++j)
                    s = fmaf(qv[j], Ks[k][sub * 16 + j], s);
                s += __shfl_xor(s, 1);
                s += __shfl_xor(s, 2);
                s = (kmsh[k] != 0.f) ? s : -INFINITY;
                if ((k & 3) == sub) sreg[k >> 2] = s;
            }
            float tm = sreg[0];
            #pragma unroll
            for (int j = 1; j < 16; ++j) tm = fmaxf(tm, sreg[j]);
            tm = fmaxf(tm, __shfl_xor(tm, 1));
            tm = fmaxf(tm, __shfl_xor(tm, 2));
            float mnew = fmaxf(mx, tm);
            if (mnew != -INFINITY) {       // skip if nothing valid yet (avoid NaN)
                float f = __expf(mx - mnew);   // exp(-inf)=0 handles first tile
                float p[16];
                float psum = 0.f;
                #pragma unroll
                for (int j = 0; j < 16; ++j) {
                    p[j] = __expf(sreg[j] - mnew);   // masked -> exp(-inf)=0
                    psum += p[j];
                }
                psum += __shfl_xor(psum, 1);
                psum += __shfl_xor(psum, 2);
                sm = sm * f + psum;
                #pragma unroll
                for (int j = 0; j < 16; ++j) Ps[row][j * 4 + sub] = p[j];
                #pragma unroll
                for (int j = 0; j < 16; ++j) o[j] *= f;
                // same-wave DS ordering makes Ps visible to the 4-lane group
                #pragma unroll 4
                for (int k = 0; k < 64; ++k) {
                    float pk = Ps[row][k];
                    #pragma unroll
                    for (int j = 0; j < 16; ++j)
                        o[j] = fmaf(pk, Vs[k][sub * 16 + j], o[j]);
                }
                mx = mnew;
            }
        }
        __syncthreads();
    }

    float inv = (qm && sm > 0.f) ? (1.0f / sm) : 0.f;
    float* op = O + (size_t)(b * T_SEQ + tq) * EMB + h * HS + sub * 16;
    #pragma unroll
    for (int j = 0; j < 4; ++j) {
        float4 v4 = make_float4(o[j * 4 + 0] * inv, o[j * 4 + 1] * inv,
                                o[j * 4 + 2] * inv, o[j * 4 + 3] * inv);
        *(float4*)(op + j * 4) = v4;
    }
}

// ---------------------------------------------------------------------------
extern "C" void kernel_launch(void* const* d_in, const int* in_sizes, int n_in,
                              void* d_out, int out_size, void* d_ws, size_t ws_size,
                              hipStream_t stream)
{
    const float* x    = (const float*)d_in[0];
    const int*   mask = (const int*)d_in[1];
    const float* Wk   = (const float*)d_in[2];
    const float* Wq   = (const float*)d_in[3];
    const float* Wv   = (const float*)d_in[4];
    const float* Wo   = (const float*)d_in[5];
    const float* bo   = (const float*)d_in[6];
    const float* kg   = (const float*)d_in[7];
    const float* kbb  = (const float*)d_in[8];
    const float* qg   = (const float*)d_in[9];
    const float* qbb  = (const float*)d_in[10];
    float* out = (float*)d_out;

    const size_t NELT = (size_t)M_TOT * EMB;   // 8,388,608 elements
    float* qbuf = (float*)d_ws;
    float* kbuf = qbuf + NELT;
    float* vbuf = kbuf + NELT;
    float* abuf = vbuf + NELT;

    const float ps = 0.17677669529663687f;     // 1024^(-1/4)

    dim3 ggrid(M_TOT / GT, EMB / GT);
    gemm_xwt<<<ggrid, 256, 0, stream>>>(x, Wq, qbuf, EMB, qg, qbb, ps, nullptr, 1);
    gemm_xwt<<<ggrid, 256, 0, stream>>>(x, Wk, kbuf, EMB, kg, kbb, ps, nullptr, 1);
    gemm_xwt<<<ggrid, 256, 0, stream>>>(x, Wv, vbuf, EMB, nullptr, nullptr, 1.f, nullptr, 0);

    dim3 agrid(T_SEQ / 64, HEADS, B_SZ);
    attn_fwd<<<agrid, 256, 0, stream>>>(qbuf, kbuf, vbuf, mask, abuf);

    gemm_xwt<<<ggrid, 256, 0, stream>>>(abuf, Wo, out, EMB, nullptr, nullptr, 1.f, bo, 0);
}

// Round 2
// 1950.011 us; speedup vs baseline: 2.0369x; 2.0369x over previous
//
#include <hip/hip_runtime.h>
#include <math.h>

#define B_SZ   4
#define T_SEQ  2048
#define EMB    1024
#define HEADS  16
#define HS     64
#define M_TOT  (B_SZ * T_SEQ)   // 8192

using f32x4  = __attribute__((ext_vector_type(4))) float;
using bf16x8 = __attribute__((ext_vector_type(8))) short;   // 8 bf16 in 4 VGPRs

// async global->LDS, 16B per lane; LDS dest is wave-uniform base + lane*16
__device__ __forceinline__ void async16(unsigned short* lds, const unsigned short* g) {
    __builtin_amdgcn_global_load_lds(
        (const __attribute__((address_space(1))) unsigned int*)g,
        (__attribute__((address_space(3))) unsigned int*)lds, 16, 0, 0);
}

// ---------------------------------------------------------------------------
// split fp32 -> (hi bf16, lo bf16), RNE. 4 elems/thread.
// ---------------------------------------------------------------------------
__global__ __launch_bounds__(256) void split_bf16(
    const float* __restrict__ in, unsigned short* __restrict__ hi,
    unsigned short* __restrict__ lo, int n4)
{
    int i = blockIdx.x * blockDim.x + threadIdx.x;
    if (i >= n4) return;
    float4 v = ((const float4*)in)[i];
    float f[4] = {v.x, v.y, v.z, v.w};
    unsigned short hh[4], ll[4];
    #pragma unroll
    for (int j = 0; j < 4; ++j) {
        unsigned u = __float_as_uint(f[j]);
        unsigned short h = (unsigned short)((u + 0x7fffu + ((u >> 16) & 1u)) >> 16);
        float hf = __uint_as_float(((unsigned)h) << 16);
        float r = f[j] - hf;
        unsigned u2 = __float_as_uint(r);
        ll[j] = (unsigned short)((u2 + 0x7fffu + ((u2 >> 16) & 1u)) >> 16);
        hh[j] = h;
    }
    uint2 H, L;
    H.x = (unsigned)hh[0] | ((unsigned)hh[1] << 16);
    H.y = (unsigned)hh[2] | ((unsigned)hh[3] << 16);
    L.x = (unsigned)ll[0] | ((unsigned)ll[1] << 16);
    L.y = (unsigned)ll[2] | ((unsigned)ll[3] << 16);
    ((uint2*)hi)[i] = H;
    ((uint2*)lo)[i] = L;
}

// ---------------------------------------------------------------------------
// Split-bf16 MFMA GEMM: C = A @ W^T (A: MxK, W: NxK, both as hi/lo bf16).
// acc += Ah*Wh + Ah*Wl + Al*Wh   (3 MFMAs per frag pair, ~fp32 accuracy)
// 128x128 tile, BK=32, 256 thr = 4 waves (2x2), each wave 64x64 = 4x4 frags.
// Optional fused per-head LN (wave's 64-col sub-tile == one head) + bias.
// ---------------------------------------------------------------------------
#define BM 128
#define BN 128
#define BKB 32

__global__ __launch_bounds__(256, 2) void gemm_mfma(
    const unsigned short* __restrict__ Ah, const unsigned short* __restrict__ Al,
    const unsigned short* __restrict__ Wh, const unsigned short* __restrict__ Wl,
    float* __restrict__ C,
    const float* __restrict__ lng, const float* __restrict__ lnb,
    float post_scale, const float* __restrict__ bias, int do_ln)
{
    __shared__ unsigned short sAh[BM * BKB], sAl[BM * BKB];
    __shared__ unsigned short sBh[BN * BKB], sBl[BN * BKB];
    const int tid = threadIdx.x;
    const int w = tid >> 6, lane = tid & 63;
    const int wr = w >> 1, wc = w & 1;
    const int m0 = blockIdx.x * BM, n0 = blockIdx.y * BN;
    const int fr = lane & 15, kc = (lane >> 4) * 8;
    const int srow = lane >> 2, schunk = (lane & 3) * 8;

    f32x4 acc[4][4] = {};

    for (int k0 = 0; k0 < EMB; k0 += BKB) {
        #pragma unroll
        for (int c = 0; c < 2; ++c) {
            int r = (w * 2 + c) * 16 + srow;          // row within 128-tile
            size_t gA = (size_t)(m0 + r) * EMB + k0 + schunk;
            size_t gB = (size_t)(n0 + r) * EMB + k0 + schunk;
            int lb = (w * 2 + c) * 512;               // shorts (1KB per call)
            async16(&sAh[lb], Ah + gA);
            async16(&sAl[lb], Al + gA);
            async16(&sBh[lb], Wh + gB);
            async16(&sBl[lb], Wl + gB);
        }
        __syncthreads();   // compiler drains vmcnt before s_barrier

        bf16x8 bh[4], bl[4];
        #pragma unroll
        for (int ni = 0; ni < 4; ++ni) {
            int row = wc * 64 + ni * 16 + fr;
            bh[ni] = *(const bf16x8*)&sBh[row * BKB + kc];
            bl[ni] = *(const bf16x8*)&sBl[row * BKB + kc];
        }
        #pragma unroll
        for (int mi = 0; mi < 4; ++mi) {
            int row = wr * 64 + mi * 16 + fr;
            bf16x8 ah = *(const bf16x8*)&sAh[row * BKB + kc];
            bf16x8 al = *(const bf16x8*)&sAl[row * BKB + kc];
            #pragma unroll
            for (int ni = 0; ni < 4; ++ni) {
                acc[mi][ni] = __builtin_amdgcn_mfma_f32_16x16x32_bf16(ah, bh[ni], acc[mi][ni], 0, 0, 0);
                acc[mi][ni] = __builtin_amdgcn_mfma_f32_16x16x32_bf16(ah, bl[ni], acc[mi][ni], 0, 0, 0);
                acc[mi][ni] = __builtin_amdgcn_mfma_f32_16x16x32_bf16(al, bh[ni], acc[mi][ni], 0, 0, 0);
            }
        }
        __syncthreads();
    }

    if (do_ln) {
        float g4[4], b4[4];
        #pragma unroll
        for (int ni = 0; ni < 4; ++ni) {
            int dd = ni * 16 + fr;                    // feature within head
            g4[ni] = lng[dd];
            b4[ni] = lnb[dd];
        }
        #pragma unroll
        for (int mi = 0; mi < 4; ++mi) {
            #pragma unroll
            for (int i = 0; i < 4; ++i) {
                float s = acc[mi][0][i] + acc[mi][1][i] + acc[mi][2][i] + acc[mi][3][i];
                #pragma unroll
                for (int off = 1; off < 16; off <<= 1) s += __shfl_xor(s, off);
                float mu = s * (1.f / HS);
                float d2 = 0.f;
                #pragma unroll
                for (int ni = 0; ni < 4; ++ni) {
                    float d = acc[mi][ni][i] - mu;
                    d2 += d * d;
                }
                #pragma unroll
                for (int off = 1; off < 16; off <<= 1) d2 += __shfl_xor(d2, off);
                float rs = rsqrtf(d2 * (1.f / HS) + 1e-5f);
                #pragma unroll
                for (int ni = 0; ni < 4; ++ni)
                    acc[mi][ni][i] = ((acc[mi][ni][i] - mu) * rs * g4[ni] + b4[ni]) * post_scale;
            }
        }
    }

    #pragma unroll
    for (int mi = 0; mi < 4; ++mi) {
        #pragma unroll
        for (int ni = 0; ni < 4; ++ni) {
            int col = n0 + wc * 64 + ni * 16 + fr;
            int rowb = m0 + wr * 64 + mi * 16 + (lane >> 4) * 4;
            float badd = bias ? bias[col] : 0.f;
            #pragma unroll
            for (int i = 0; i < 4; ++i)
                C[(size_t)(rowb + i) * EMB + col] = acc[mi][ni][i] + badd;
        }
    }
}

// ---------------------------------------------------------------------------
// Flash attention, fp32 (unchanged from round 1).
// ---------------------------------------------------------------------------
__global__ __launch_bounds__(256) void attn_fwd(
    const float* __restrict__ Q, const float* __restrict__ K,
    const float* __restrict__ V, const int* __restrict__ mask,
    float* __restrict__ O)
{
    __shared__ float Ks[64][68];
    __shared__ float Vs[64][68];
    __shared__ float Ps[64][65];
    __shared__ float kmsh[64];
    const int tid = threadIdx.x;
    const int qt = blockIdx.x, h = blockIdx.y, b = blockIdx.z;
    const int row = tid >> 2, sub = tid & 3;
    const int tq = qt * 64 + row;
    const int qm = mask[b * T_SEQ + tq];

    float qv[16];
    {
        const float* qp = Q + (size_t)(b * T_SEQ + tq) * EMB + h * HS + sub * 16;
        #pragma unroll
        for (int j = 0; j < 4; ++j) {
            float4 t4 = *(const float4*)(qp + j * 4);
            qv[j * 4 + 0] = t4.x; qv[j * 4 + 1] = t4.y;
            qv[j * 4 + 2] = t4.z; qv[j * 4 + 3] = t4.w;
        }
    }
    float mx = -INFINITY, sm = 0.f;
    float o[16];
    #pragma unroll
    for (int j = 0; j < 16; ++j) o[j] = 0.f;

    for (int kt = 0; kt < T_SEQ / 64; ++kt) {
        #pragma unroll
        for (int i = 0; i < 4; ++i) {
            int f = tid + i * 256;
            int r = f >> 4, c = (f & 15) << 2;
            size_t g = (size_t)(b * T_SEQ + kt * 64 + r) * EMB + h * HS + c;
            *(float4*)&Ks[r][c] = *(const float4*)(K + g);
            *(float4*)&Vs[r][c] = *(const float4*)(V + g);
        }
        if (tid < 64) kmsh[tid] = (float)mask[b * T_SEQ + kt * 64 + tid];
        __syncthreads();

        if (qm) {
            float sreg[16];
            #pragma unroll
            for (int k = 0; k < 64; ++k) {
                float s = 0.f;
                #pragma unroll
                for (int j = 0; j < 16; ++j)
                    s = fmaf(qv[j], Ks[k][sub * 16 + j], s);
                s += __shfl_xor(s, 1);
                s += __shfl_xor(s, 2);
                s = (kmsh[k] != 0.f) ? s : -INFINITY;
                if ((k & 3) == sub) sreg[k >> 2] = s;
            }
            float tm = sreg[0];
            #pragma unroll
            for (int j = 1; j < 16; ++j) tm = fmaxf(tm, sreg[j]);
            tm = fmaxf(tm, __shfl_xor(tm, 1));
            tm = fmaxf(tm, __shfl_xor(tm, 2));
            float mnew = fmaxf(mx, tm);
            if (mnew != -INFINITY) {
                float f = __expf(mx - mnew);
                float p[16];
                float psum = 0.f;
                #pragma unroll
                for (int j = 0; j < 16; ++j) {
                    p[j] = __expf(sreg[j] - mnew);
                    psum += p[j];
                }
                psum += __shfl_xor(psum, 1);
                psum += __shfl_xor(psum, 2);
                sm = sm * f + psum;
                #pragma unroll
                for (int j = 0; j < 16; ++j) Ps[row][j * 4 + sub] = p[j];
                #pragma unroll
                for (int j = 0; j < 16; ++j) o[j] *= f;
                #pragma unroll 4
                for (int k = 0; k < 64; ++k) {
                    float pk = Ps[row][k];
                    #pragma unroll
                    for (int j = 0; j < 16; ++j)
                        o[j] = fmaf(pk, Vs[k][sub * 16 + j], o[j]);
                }
                mx = mnew;
            }
        }
        __syncthreads();
    }

    float inv = (qm && sm > 0.f) ? (1.0f / sm) : 0.f;
    float* op = O + (size_t)(b * T_SEQ + tq) * EMB + h * HS + sub * 16;
    #pragma unroll
    for (int j = 0; j < 4; ++j) {
        float4 v4 = make_float4(o[j * 4 + 0] * inv, o[j * 4 + 1] * inv,
                                o[j * 4 + 2] * inv, o[j * 4 + 3] * inv);
        *(float4*)(op + j * 4) = v4;
    }
}

// ---------------------------------------------------------------------------
extern "C" void kernel_launch(void* const* d_in, const int* in_sizes, int n_in,
                              void* d_out, int out_size, void* d_ws, size_t ws_size,
                              hipStream_t stream)
{
    const float* x    = (const float*)d_in[0];
    const int*   mask = (const int*)d_in[1];
    const float* Wk   = (const float*)d_in[2];
    const float* Wq   = (const float*)d_in[3];
    const float* Wv   = (const float*)d_in[4];
    const float* Wo   = (const float*)d_in[5];
    const float* bo   = (const float*)d_in[6];
    const float* kg   = (const float*)d_in[7];
    const float* kbb  = (const float*)d_in[8];
    const float* qg   = (const float*)d_in[9];
    const float* qbb  = (const float*)d_in[10];
    float* out = (float*)d_out;

    const size_t NELT = (size_t)M_TOT * EMB;        // 8,388,608
    const size_t WELT = (size_t)EMB * EMB;          // 1,048,576
    float* qbuf = (float*)d_ws;
    float* kbuf = qbuf + NELT;
    float* vbuf = kbuf + NELT;
    float* abuf = vbuf + NELT;
    unsigned short* xh  = (unsigned short*)(abuf + NELT);
    unsigned short* xl  = xh + NELT;
    unsigned short* wqh = xl + NELT;
    unsigned short* wql = wqh + WELT;
    unsigned short* wkh = wql + WELT;
    unsigned short* wkl = wkh + WELT;
    unsigned short* wvh = wkl + WELT;
    unsigned short* wvl = wvh + WELT;
    unsigned short* woh = wvl + WELT;
    unsigned short* wol = woh + WELT;

    const float ps = 0.17677669529663687f;          // 1024^(-1/4)

    split_bf16<<<(int)(NELT / 4 + 255) / 256, 256, 0, stream>>>(x, xh, xl, (int)(NELT / 4));
    split_bf16<<<(int)(WELT / 4 + 255) / 256, 256, 0, stream>>>(Wq, wqh, wql, (int)(WELT / 4));
    split_bf16<<<(int)(WELT / 4 + 255) / 256, 256, 0, stream>>>(Wk, wkh, wkl, (int)(WELT / 4));
    split_bf16<<<(int)(WELT / 4 + 255) / 256, 256, 0, stream>>>(Wv, wvh, wvl, (int)(WELT / 4));
    split_bf16<<<(int)(WELT / 4 + 255) / 256, 256, 0, stream>>>(Wo, woh, wol, (int)(WELT / 4));

    dim3 ggrid(M_TOT / BM, EMB / BN);
    gemm_mfma<<<ggrid, 256, 0, stream>>>(xh, xl, wqh, wql, qbuf, qg, qbb, ps, nullptr, 1);
    gemm_mfma<<<ggrid, 256, 0, stream>>>(xh, xl, wkh, wkl, kbuf, kg, kbb, ps, nullptr, 1);
    gemm_mfma<<<ggrid, 256, 0, stream>>>(xh, xl, wvh, wvl, vbuf, nullptr, nullptr, 1.f, nullptr, 0);

    dim3 agrid(T_SEQ / 64, HEADS, B_SZ);
    attn_fwd<<<agrid, 256, 0, stream>>>(qbuf, kbuf, vbuf, mask, abuf);

    // split attention output into bf16 hi/lo (reuse xh/xl region)
    split_bf16<<<(int)(NELT / 4 + 255) / 256, 256, 0, stream>>>(abuf, xh, xl, (int)(NELT / 4));
    gemm_mfma<<<ggrid, 256, 0, stream>>>(xh, xl, woh, wol, out, nullptr, nullptr, 1.f, bo, 0);
}

// Round 3
// 550.709 us; speedup vs baseline: 7.2125x; 3.5409x over previous
//
#include <hip/hip_runtime.h>
#include <math.h>

#define B_SZ   4
#define T_SEQ  2048
#define EMB    1024
#define HEADS  16
#define HS     64
#define M_TOT  (B_SZ * T_SEQ)   // 8192

typedef unsigned short u16;
using f32x4  = __attribute__((ext_vector_type(4))) float;
using bf16x8 = __attribute__((ext_vector_type(8))) short;
using u16x8  = __attribute__((ext_vector_type(8))) unsigned short;
using u16x4  = __attribute__((ext_vector_type(4))) unsigned short;

// async global->LDS, 16B per lane; LDS dest is wave-uniform base + lane*16
__device__ __forceinline__ void async16(u16* lds, const u16* g) {
    __builtin_amdgcn_global_load_lds(
        (const __attribute__((address_space(1))) unsigned int*)g,
        (__attribute__((address_space(3))) unsigned int*)lds, 16, 0, 0);
}

__device__ __forceinline__ u16 bf16_rne(float f) {
    unsigned u = __float_as_uint(f);
    return (u16)((u + 0x7fffu + ((u >> 16) & 1u)) >> 16);
}
__device__ __forceinline__ void split2(float f, u16& h, u16& l) {
    h = bf16_rne(f);
    float hf = __uint_as_float(((unsigned)h) << 16);
    l = bf16_rne(f - hf);
}
__device__ __forceinline__ unsigned cvt_pk_bf16(float a, float b) {
    unsigned r;
    asm("v_cvt_pk_bf16_f32 %0, %1, %2" : "=v"(r) : "v"(a), "v"(b));
    return r;
}

// ---------------------------------------------------------------------------
// split fp32 -> (hi bf16, lo bf16), RNE. 4 elems/thread.
// ---------------------------------------------------------------------------
__global__ __launch_bounds__(256) void split_bf16(
    const float* __restrict__ in, u16* __restrict__ hi,
    u16* __restrict__ lo, int n4)
{
    int i = blockIdx.x * blockDim.x + threadIdx.x;
    if (i >= n4) return;
    float4 v = ((const float4*)in)[i];
    float f[4] = {v.x, v.y, v.z, v.w};
    u16 hh[4], ll[4];
    #pragma unroll
    for (int j = 0; j < 4; ++j) split2(f[j], hh[j], ll[j]);
    uint2 H, L;
    H.x = (unsigned)hh[0] | ((unsigned)hh[1] << 16);
    H.y = (unsigned)hh[2] | ((unsigned)hh[3] << 16);
    L.x = (unsigned)ll[0] | ((unsigned)ll[1] << 16);
    L.y = (unsigned)ll[2] | ((unsigned)ll[3] << 16);
    ((uint2*)hi)[i] = H;
    ((uint2*)lo)[i] = L;
}

// ---------------------------------------------------------------------------
// Split-bf16 MFMA GEMM: C = A @ W^T (A: MxK, W: NxK, both hi/lo bf16).
// mode 0: fp32 out [M][EMB] + bias
// mode 1: per-head LN + post_scale, out as hi/lo bf16 [M][EMB]
// mode 2: out as hi/lo bf16 TRANSPOSED Vt[b][h][d][t]  (for attention PV)
// ---------------------------------------------------------------------------
#define BM 128
#define BN 128
#define BKB 32

__global__ __launch_bounds__(256, 2) void gemm_mfma(
    const u16* __restrict__ Ah, const u16* __restrict__ Al,
    const u16* __restrict__ Wh, const u16* __restrict__ Wl,
    float* __restrict__ Cf, u16* __restrict__ Chi, u16* __restrict__ Clo,
    const float* __restrict__ lng, const float* __restrict__ lnb,
    float post_scale, const float* __restrict__ bias, int mode)
{
    __shared__ u16 sAh[BM * BKB], sAl[BM * BKB];
    __shared__ u16 sBh[BN * BKB], sBl[BN * BKB];
    const int tid = threadIdx.x;
    const int w = tid >> 6, lane = tid & 63;
    const int wr = w >> 1, wc = w & 1;
    const int m0 = blockIdx.x * BM, n0 = blockIdx.y * BN;
    const int fr = lane & 15, kc = (lane >> 4) * 8;
    const int srow = lane >> 2, schunk = (lane & 3) * 8;

    f32x4 acc[4][4] = {};

    for (int k0 = 0; k0 < EMB; k0 += BKB) {
        #pragma unroll
        for (int c = 0; c < 2; ++c) {
            int r = (w * 2 + c) * 16 + srow;
            size_t gA = (size_t)(m0 + r) * EMB + k0 + schunk;
            size_t gB = (size_t)(n0 + r) * EMB + k0 + schunk;
            int lb = (w * 2 + c) * 512;
            async16(&sAh[lb], Ah + gA);
            async16(&sAl[lb], Al + gA);
            async16(&sBh[lb], Wh + gB);
            async16(&sBl[lb], Wl + gB);
        }
        __syncthreads();

        bf16x8 bh[4], bl[4];
        #pragma unroll
        for (int ni = 0; ni < 4; ++ni) {
            int row = wc * 64 + ni * 16 + fr;
            bh[ni] = *(const bf16x8*)&sBh[row * BKB + kc];
            bl[ni] = *(const bf16x8*)&sBl[row * BKB + kc];
        }
        #pragma unroll
        for (int mi = 0; mi < 4; ++mi) {
            int row = wr * 64 + mi * 16 + fr;
            bf16x8 ah = *(const bf16x8*)&sAh[row * BKB + kc];
            bf16x8 al = *(const bf16x8*)&sAl[row * BKB + kc];
            #pragma unroll
            for (int ni = 0; ni < 4; ++ni) {
                acc[mi][ni] = __builtin_amdgcn_mfma_f32_16x16x32_bf16(ah, bh[ni], acc[mi][ni], 0, 0, 0);
                acc[mi][ni] = __builtin_amdgcn_mfma_f32_16x16x32_bf16(ah, bl[ni], acc[mi][ni], 0, 0, 0);
                acc[mi][ni] = __builtin_amdgcn_mfma_f32_16x16x32_bf16(al, bh[ni], acc[mi][ni], 0, 0, 0);
            }
        }
        __syncthreads();
    }

    if (mode == 1) {
        float g4[4], b4[4];
        #pragma unroll
        for (int ni = 0; ni < 4; ++ni) {
            int dd = ni * 16 + fr;
            g4[ni] = lng[dd];
            b4[ni] = lnb[dd];
        }
        #pragma unroll
        for (int mi = 0; mi < 4; ++mi) {
            #pragma unroll
            for (int i = 0; i < 4; ++i) {
                float s = acc[mi][0][i] + acc[mi][1][i] + acc[mi][2][i] + acc[mi][3][i];
                #pragma unroll
                for (int off = 1; off < 16; off <<= 1) s += __shfl_xor(s, off);
                float mu = s * (1.f / HS);
                float d2 = 0.f;
                #pragma unroll
                for (int ni = 0; ni < 4; ++ni) {
                    float d = acc[mi][ni][i] - mu;
                    d2 += d * d;
                }
                #pragma unroll
                for (int off = 1; off < 16; off <<= 1) d2 += __shfl_xor(d2, off);
                float rs = rsqrtf(d2 * (1.f / HS) + 1e-5f);
                #pragma unroll
                for (int ni = 0; ni < 4; ++ni)
                    acc[mi][ni][i] = ((acc[mi][ni][i] - mu) * rs * g4[ni] + b4[ni]) * post_scale;
            }
        }
    }

    #pragma unroll
    for (int mi = 0; mi < 4; ++mi) {
        #pragma unroll
        for (int ni = 0; ni < 4; ++ni) {
            const int col = n0 + wc * 64 + ni * 16 + fr;
            const int rowb = m0 + wr * 64 + mi * 16 + (lane >> 4) * 4;
            if (mode == 0) {
                float badd = bias[col];
                #pragma unroll
                for (int i = 0; i < 4; ++i)
                    Cf[(size_t)(rowb + i) * EMB + col] = acc[mi][ni][i] + badd;
            } else if (mode == 1) {
                #pragma unroll
                for (int i = 0; i < 4; ++i) {
                    u16 hh, ll; split2(acc[mi][ni][i], hh, ll);
                    Chi[(size_t)(rowb + i) * EMB + col] = hh;
                    Clo[(size_t)(rowb + i) * EMB + col] = ll;
                }
            } else {
                int hh = col >> 6, d = col & 63;
                int bb = rowb >> 11, t0 = rowb & 2047;
                u16x4 H, L;
                #pragma unroll
                for (int i = 0; i < 4; ++i) {
                    u16 vh, vl; split2(acc[mi][ni][i], vh, vl);
                    H[i] = vh; L[i] = vl;
                }
                size_t off = ((size_t)((bb * HEADS + hh) * HS + d)) * T_SEQ + t0;
                *(u16x4*)(Chi + off) = H;
                *(u16x4*)(Clo + off) = L;
            }
        }
    }
}

// ---------------------------------------------------------------------------
// MFMA flash attention. Block = (128 q-rows, head, batch), 4 waves (32 q each).
// Swapped QK^T (mfma(K,Q)) -> in-reg softmax; P via cvt_pk + LDS; PV with
// pre-transposed V. Split-bf16: QK 3 MFMAs, PV 2 (P bf16, V hi/lo).
// ---------------------------------------------------------------------------
__global__ __launch_bounds__(256, 2) void attn_mfma(
    const u16* __restrict__ qh, const u16* __restrict__ ql,
    const u16* __restrict__ kh, const u16* __restrict__ kl,
    const u16* __restrict__ vh, const u16* __restrict__ vl,
    const int* __restrict__ mask,
    u16* __restrict__ oh, u16* __restrict__ ol)
{
    __shared__ u16 sKh[64 * 72], sKl[64 * 72], sVh[64 * 72], sVl[64 * 72];
    __shared__ u16 sPs[4][32 * 72];
    __shared__ float kmsh[64];
    __shared__ float qmsh[128];
    __shared__ float fb[4][32];

    const int tid = threadIdx.x;
    const int w = tid >> 6, lane = tid & 63;
    const int fr = lane & 15, g = lane >> 4;
    const int q0 = blockIdx.x * 128;
    const int h = blockIdx.y, b = blockIdx.z;

    if (tid < 128) qmsh[tid] = (float)mask[b * T_SEQ + q0 + tid];

    // per-wave staging assignment: w0->Kh, w1->Kl, w2->Vh(T), w3->Vl(T)
    const u16* ksrc; u16* sdst; size_t rstr, kstp;
    if (w < 2) {
        ksrc = (w == 0 ? kh : kl) + (size_t)b * T_SEQ * EMB + h * HS;
        sdst = (w == 0 ? sKh : sKl);
        rstr = EMB; kstp = (size_t)64 * EMB;
    } else {
        ksrc = (w == 2 ? vh : vl) + (size_t)(b * HEADS + h) * HS * T_SEQ;
        sdst = (w == 2 ? sVh : sVl);
        rstr = T_SEQ; kstp = 64;
    }

    // Q fragments in registers (B-operand of swapped QK^T)
    bf16x8 qfh[2][2], qfl[2][2];
    #pragma unroll
    for (int nf = 0; nf < 2; ++nf)
        #pragma unroll
        for (int ks = 0; ks < 2; ++ks) {
            size_t off = (size_t)(b * T_SEQ + q0 + w * 32 + nf * 16 + fr) * EMB
                         + h * HS + g * 8 + ks * 32;
            qfh[nf][ks] = *(const bf16x8*)(qh + off);
            qfl[nf][ks] = *(const bf16x8*)(ql + off);
        }

    f32x4 o[2][4] = {};
    float mrun[2] = {-INFINITY, -INFINITY}, lrun[2] = {0.f, 0.f};
    u16* Psw = sPs[w];

    for (int kt = 0; kt < T_SEQ / 64; ++kt) {
        // ---- stage K/V tile (each wave one buffer) ----
        const u16* src = ksrc + (size_t)kt * kstp;
        u16x8 stg[8];
        #pragma unroll
        for (int it = 0; it < 8; ++it) {
            int idx = it * 64 + lane;
            stg[it] = *(const u16x8*)(src + (size_t)(idx >> 3) * rstr + (idx & 7) * 8);
        }
        #pragma unroll
        for (int it = 0; it < 8; ++it) {
            int idx = it * 64 + lane;
            *(u16x8*)&sdst[(idx >> 3) * 72 + (idx & 7) * 8] = stg[it];
        }
        if (tid < 64) kmsh[tid] = (float)mask[b * T_SEQ + kt * 64 + tid];
        __syncthreads();

        float kmv[4][4]; int anyv = 0;
        #pragma unroll
        for (int mf = 0; mf < 4; ++mf)
            #pragma unroll
            for (int i = 0; i < 4; ++i) {
                kmv[mf][i] = kmsh[mf * 16 + g * 4 + i];
                anyv |= (kmv[mf][i] != 0.f);
            }

        if (__any(anyv)) {
            // ---- QK^T (swapped): st[key][q] ----
            f32x4 st[4][2] = {};
            #pragma unroll
            for (int ks = 0; ks < 2; ++ks) {
                bf16x8 ka[4], kb[4];
                #pragma unroll
                for (int mf = 0; mf < 4; ++mf) {
                    ka[mf] = *(const bf16x8*)&sKh[(mf * 16 + fr) * 72 + g * 8 + ks * 32];
                    kb[mf] = *(const bf16x8*)&sKl[(mf * 16 + fr) * 72 + g * 8 + ks * 32];
                }
                #pragma unroll
                for (int mf = 0; mf < 4; ++mf)
                    #pragma unroll
                    for (int nf = 0; nf < 2; ++nf) {
                        st[mf][nf] = __builtin_amdgcn_mfma_f32_16x16x32_bf16(ka[mf], qfh[nf][ks], st[mf][nf], 0, 0, 0);
                        st[mf][nf] = __builtin_amdgcn_mfma_f32_16x16x32_bf16(ka[mf], qfl[nf][ks], st[mf][nf], 0, 0, 0);
                        st[mf][nf] = __builtin_amdgcn_mfma_f32_16x16x32_bf16(kb[mf], qfh[nf][ks], st[mf][nf], 0, 0, 0);
                    }
            }
            // ---- online softmax (per q = lane&15 + 16*nf) ----
            #pragma unroll
            for (int nf = 0; nf < 2; ++nf) {
                float tm = -INFINITY;
                #pragma unroll
                for (int mf = 0; mf < 4; ++mf)
                    #pragma unroll
                    for (int i = 0; i < 4; ++i) {
                        float s = (kmv[mf][i] != 0.f) ? st[mf][nf][i] : -INFINITY;
                        st[mf][nf][i] = s;
                        tm = fmaxf(tm, s);
                    }
                tm = fmaxf(tm, __shfl_xor(tm, 16));
                tm = fmaxf(tm, __shfl_xor(tm, 32));
                float mn = fmaxf(mrun[nf], tm);
                float f = __expf(mrun[nf] - mn);     // exp(-inf)=0 on first tile
                float ps = 0.f;
                #pragma unroll
                for (int mf = 0; mf < 4; ++mf)
                    #pragma unroll
                    for (int i = 0; i < 4; ++i) {
                        float p = __expf(st[mf][nf][i] - mn);
                        st[mf][nf][i] = p;
                        ps += p;
                    }
                ps += __shfl_xor(ps, 16);
                ps += __shfl_xor(ps, 32);
                lrun[nf] = lrun[nf] * f + ps;
                mrun[nf] = mn;
                fb[w][nf * 16 + fr] = f;             // broadcast f per q
            }
            // ---- P -> bf16 -> LDS (A-operand layout for PV) ----
            #pragma unroll
            for (int nf = 0; nf < 2; ++nf)
                #pragma unroll
                for (int mf = 0; mf < 4; ++mf)
                    #pragma unroll
                    for (int i = 0; i < 4; i += 2) {
                        unsigned pk = cvt_pk_bf16(st[mf][nf][i], st[mf][nf][i + 1]);
                        *(unsigned*)&Psw[(nf * 16 + fr) * 72 + mf * 16 + g * 4 + i] = pk;
                    }
            // ---- rescale O by f (O-layout q = (lane>>4)*4+i+16*mi) ----
            float ff[2][4];
            #pragma unroll
            for (int mi = 0; mi < 2; ++mi)
                #pragma unroll
                for (int i = 0; i < 4; ++i)
                    ff[mi][i] = fb[w][mi * 16 + g * 4 + i];
            #pragma unroll
            for (int mi = 0; mi < 2; ++mi)
                #pragma unroll
                for (int nj = 0; nj < 4; ++nj)
                    #pragma unroll
                    for (int i = 0; i < 4; ++i)
                        o[mi][nj][i] *= ff[mi][i];
            // ---- PV ----
            #pragma unroll
            for (int ks = 0; ks < 2; ++ks) {
                bf16x8 pa[2];
                #pragma unroll
                for (int mi = 0; mi < 2; ++mi)
                    pa[mi] = *(const bf16x8*)&Psw[(mi * 16 + fr) * 72 + g * 8 + ks * 32];
                #pragma unroll
                for (int nj = 0; nj < 4; ++nj) {
                    bf16x8 va = *(const bf16x8*)&sVh[(nj * 16 + fr) * 72 + g * 8 + ks * 32];
                    bf16x8 vb = *(const bf16x8*)&sVl[(nj * 16 + fr) * 72 + g * 8 + ks * 32];
                    #pragma unroll
                    for (int mi = 0; mi < 2; ++mi) {
                        o[mi][nj] = __builtin_amdgcn_mfma_f32_16x16x32_bf16(pa[mi], va, o[mi][nj], 0, 0, 0);
                        o[mi][nj] = __builtin_amdgcn_mfma_f32_16x16x32_bf16(pa[mi], vb, o[mi][nj], 0, 0, 0);
                    }
                }
            }
        }
        __syncthreads();
    }

    // ---- epilogue: normalize, mask q, write hi/lo bf16 ----
    #pragma unroll
    for (int nf = 0; nf < 2; ++nf) fb[w][nf * 16 + fr] = lrun[nf];
    #pragma unroll
    for (int mi = 0; mi < 2; ++mi)
        #pragma unroll
        for (int i = 0; i < 4; ++i) {
            float lq = fb[w][mi * 16 + g * 4 + i];
            float qv = qmsh[w * 32 + mi * 16 + g * 4 + i];
            float inv = (qv != 0.f && lq > 0.f) ? 1.f / lq : 0.f;
            size_t row = (size_t)(b * T_SEQ + q0 + w * 32 + mi * 16 + g * 4 + i);
            #pragma unroll
            for (int nj = 0; nj < 4; ++nj) {
                float v = o[mi][nj][i] * inv;
                u16 hh, ll; split2(v, hh, ll);
                size_t off = row * EMB + h * HS + nj * 16 + fr;
                oh[off] = hh;
                ol[off] = ll;
            }
        }
}

// ---------------------------------------------------------------------------
extern "C" void kernel_launch(void* const* d_in, const int* in_sizes, int n_in,
                              void* d_out, int out_size, void* d_ws, size_t ws_size,
                              hipStream_t stream)
{
    const float* x    = (const float*)d_in[0];
    const int*   mask = (const int*)d_in[1];
    const float* Wk   = (const float*)d_in[2];
    const float* Wq   = (const float*)d_in[3];
    const float* Wv   = (const float*)d_in[4];
    const float* Wo   = (const float*)d_in[5];
    const float* bo   = (const float*)d_in[6];
    const float* kg   = (const float*)d_in[7];
    const float* kbb  = (const float*)d_in[8];
    const float* qg   = (const float*)d_in[9];
    const float* qbb  = (const float*)d_in[10];
    float* out = (float*)d_out;

    const size_t NELT = (size_t)M_TOT * EMB;   // 8,388,608
    const size_t WELT = (size_t)EMB * EMB;     // 1,048,576
    u16* xh  = (u16*)d_ws;            // also reused as attn output hi
    u16* xl  = xh + NELT;             // also reused as attn output lo
    u16* p_qh = xl + NELT;
    u16* p_ql = p_qh + NELT;
    u16* p_kh = p_ql + NELT;
    u16* p_kl = p_kh + NELT;
    u16* p_vh = p_kl + NELT;          // transposed [b][h][d][t]
    u16* p_vl = p_vh + NELT;
    u16* wqh = p_vl + NELT;
    u16* wql = wqh + WELT;
    u16* wkh = wql + WELT;
    u16* wkl = wkh + WELT;
    u16* wvh = wkl + WELT;
    u16* wvl = wvh + WELT;
    u16* woh = wvl + WELT;
    u16* wol = woh + WELT;

    const float ps = 0.17677669529663687f;     // 1024^(-1/4)

    split_bf16<<<(int)(NELT / 4 + 255) / 256, 256, 0, stream>>>(x, xh, xl, (int)(NELT / 4));
    split_bf16<<<(int)(WELT / 4 + 255) / 256, 256, 0, stream>>>(Wq, wqh, wql, (int)(WELT / 4));
    split_bf16<<<(int)(WELT / 4 + 255) / 256, 256, 0, stream>>>(Wk, wkh, wkl, (int)(WELT / 4));
    split_bf16<<<(int)(WELT / 4 + 255) / 256, 256, 0, stream>>>(Wv, wvh, wvl, (int)(WELT / 4));
    split_bf16<<<(int)(WELT / 4 + 255) / 256, 256, 0, stream>>>(Wo, woh, wol, (int)(WELT / 4));

    dim3 ggrid(M_TOT / BM, EMB / BN);
    gemm_mfma<<<ggrid, 256, 0, stream>>>(xh, xl, wqh, wql, nullptr, p_qh, p_ql, qg, qbb, ps, nullptr, 1);
    gemm_mfma<<<ggrid, 256, 0, stream>>>(xh, xl, wkh, wkl, nullptr, p_kh, p_kl, kg, kbb, ps, nullptr, 1);
    gemm_mfma<<<ggrid, 256, 0, stream>>>(xh, xl, wvh, wvl, nullptr, p_vh, p_vl, nullptr, nullptr, 1.f, nullptr, 2);

    dim3 agrid(T_SEQ / 128, HEADS, B_SZ);
    attn_mfma<<<agrid, 256, 0, stream>>>(p_qh, p_ql, p_kh, p_kl, p_vh, p_vl, mask, xh, xl);

    gemm_mfma<<<ggrid, 256, 0, stream>>>(xh, xl, woh, wol, out, nullptr, nullptr, nullptr, nullptr, 1.f, bo, 0);
}